// Round 7
// baseline (117.909 us; speedup 1.0000x reference)
//
#include <hip/hip_runtime.h>

// SpikeDrivenSelfAttention on gfx950 — v6.
//   k_convert : f32->bf16 x, Wq|Wk|Wv; zero cnt + colsum
//   k_qkv     : 3-proj GEMM (MFMA 16x16x32, single 32KB LDS buffer) +
//               closed-form LIF threshold -> ballot-packed bit rows; V colsum
//   k_sb      : score verify with EXACT popcount prune:
//               hd(q,k) <= |q|+|k|, so only k-rows with |k| >= 53-|q| can
//               give score<12. Counting-sort k-rows desc by popcount; each n
//               scans only its qualifying prefix (~1% of pairs). + base GEMV.
//   k_out     : broadcast base rows + sparse exact correction (normally none)

typedef __attribute__((ext_vector_type(8))) short short8;
typedef __attribute__((ext_vector_type(4))) float f32x4;
typedef unsigned long long u64;

static __device__ __forceinline__ unsigned short f2bf(float f) {
  unsigned int u = __builtin_bit_cast(unsigned int, f);
  return (unsigned short)((u + 0x7FFFu + ((u >> 16) & 1u)) >> 16);
}

static __device__ __forceinline__ u64 pack4bf(float a, float b, float c, float d) {
  return (u64)f2bf(a) | ((u64)f2bf(b) << 16) | ((u64)f2bf(c) << 32) |
         ((u64)f2bf(d) << 48);
}

static __device__ __forceinline__ void gl2lds16(const unsigned short* g,
                                                unsigned short* l) {
  __builtin_amdgcn_global_load_lds(
      (const __attribute__((address_space(1))) unsigned int*)(g),
      (__attribute__((address_space(3))) unsigned int*)(l),
      16, 0, 0);
}

// ---------------- convert: f32 -> bf16 staging + zero-init ----------------
__global__ void k_convert(const float* __restrict__ x,
                          const float* __restrict__ Wq, const float* __restrict__ bq,
                          const float* __restrict__ Wk, const float* __restrict__ bk,
                          const float* __restrict__ Wv, const float* __restrict__ bv,
                          unsigned short* __restrict__ xb,
                          unsigned short* __restrict__ wcat,
                          float* __restrict__ bcat,
                          int* __restrict__ cnt,
                          float* __restrict__ colsum) {
  const int X4 = 1572864;  // 8192*768/4
  const int W4 = 147456;   // 768*768/4
  const int NB = 576;      // 2304 bias floats / 4
  const int NZ = 1536;     // 6144 colsum floats / 4
  const int total = X4 + 3 * W4 + NB + NZ;
  int t = blockIdx.x * blockDim.x + threadIdx.x;
  if (t >= total) return;
  if (t == 0) *cnt = 0;
  if (t < X4) {
    float4 v = ((const float4*)x)[t];
    *(u64*)(xb + 4 * (long)t) = pack4bf(v.x, v.y, v.z, v.w);
  } else if (t < X4 + 3 * W4) {
    int j = t - X4;
    const float* src = Wq;
    int jj = j;
    if (jj >= 2 * W4) { src = Wv; jj -= 2 * W4; }
    else if (jj >= W4) { src = Wk; jj -= W4; }
    float4 v = ((const float4*)src)[jj];
    *(u64*)(wcat + 4 * (long)j) = pack4bf(v.x, v.y, v.z, v.w);
  } else if (t < X4 + 3 * W4 + NB) {
    int j = t - (X4 + 3 * W4);  // 0..575
    int idx = j * 4;
    const float* src = bq;
    int ii = idx;
    if (ii >= 1536) { src = bv; ii -= 1536; }
    else if (ii >= 768) { src = bk; ii -= 768; }
    float4 v = *(const float4*)(src + ii);
    *(float4*)(bcat + idx) = v;
  } else {
    int j = t - (X4 + 3 * W4 + NB);  // 0..1535
    float4 z = {0.f, 0.f, 0.f, 0.f};
    ((float4*)colsum)[j] = z;
  }
}

// ---------------- QKV GEMM + threshold LIF + bit-pack + colsum ------
// grid (64, 18): 128x128 tiles over (8192 x 2304). cols: [q|k|v].
__global__ __launch_bounds__(256, 4)
void k_qkv(const unsigned short* __restrict__ xb,
           const unsigned short* __restrict__ wcat,
           const float* __restrict__ bcat,
           u64* __restrict__ bits3,     // [3][96][1024]
           float* __restrict__ colsum)  // [8][768]
{
  __shared__ __align__(16) unsigned short lA[128 * 64];
  __shared__ __align__(16) unsigned short lB[128 * 64];
  const int tid = threadIdx.x;
  const int lane = tid & 63;
  const int wid = tid >> 6;
  const int wm = wid >> 1, wn = wid & 1;
  const int row0 = blockIdx.x * 128;
  const int col0 = blockIdx.y * 128;
  const int srow = lane >> 3;
  const int scol = (lane & 7) * 8;
  const int rr = lane & 15;
  const int g = lane >> 4;
  const int g8 = g * 8;

  // hoisted per-thread staging bases (thread-invariant across K-loop)
  const unsigned short* gA = xb + (long)(row0 + wid * 32 + srow) * 768 + scol;
  const unsigned short* gB = wcat + (long)(col0 + wid * 32 + srow) * 768 + scol;
  unsigned short* sA = &lA[(wid * 32 + srow) * 64 + scol];
  unsigned short* sB = &lB[(wid * 32 + srow) * 64 + scol];

  f32x4 acc[4][4] = {};

#pragma unroll 1
  for (int kt = 0; kt < 768; kt += 64) {
    __syncthreads();
#pragma unroll
    for (int s = 0; s < 4; ++s) {
      gl2lds16(gA + s * (8 * 768) + kt, sA + s * (8 * 64));
      gl2lds16(gB + s * (8 * 768) + kt, sB + s * (8 * 64));
    }
    __syncthreads();
#pragma unroll
    for (int kk = 0; kk < 2; ++kk) {
      const int ko = kk * 32 + g8;
      short8 af[4];
#pragma unroll
      for (int i = 0; i < 4; ++i)
        af[i] = *(const short8*)&lA[(wm * 64 + i * 16 + rr) * 64 + ko];
#pragma unroll
      for (int j = 0; j < 4; ++j) {
        const short8 bf = *(const short8*)&lB[(wn * 64 + j * 16 + rr) * 64 + ko];
#pragma unroll
        for (int i = 0; i < 4; ++i)
          acc[i][j] = __builtin_amdgcn_mfma_f32_16x16x32_bf16(af[i], bf, acc[i][j], 0, 0, 0);
      }
    }
  }

  // epilogue: closed-form LIF threshold -> ballots -> bit rows (+ colsum)
  const int mi = blockIdx.y / 6;                 // 0=q,1=k,2=v
  const int h = 2 * (blockIdx.y - mi * 6) + wn;  // head 0..11 (wave-uniform)
  u64* bits = bits3 + (long)mi * 98304;          // [96][1024]
  const float C_LIF = 0.45505041f;               // 1/(1+d+d^2+d^3), d=exp(-.5)
  float thr[4];
#pragma unroll
  for (int j = 0; j < 4; ++j) thr[j] = C_LIF - bcat[col0 + wn * 64 + j * 16 + rr];

  float csum[4] = {0.f, 0.f, 0.f, 0.f};
#pragma unroll
  for (int i = 0; i < 4; ++i) {
#pragma unroll
    for (int r = 0; r < 4; ++r) {
      u64 map = 0;
#pragma unroll
      for (int j = 0; j < 4; ++j) {
        const bool sp = acc[i][j][r] >= thr[j];
        const u64 bl = __ballot(sp);
        map |= ((bl >> (g * 16)) & 0xFFFFull) << (j * 16);
        csum[j] += sp ? 1.0f : 0.0f;
      }
      if (rr == 0) {
        const int grow = row0 + wm * 64 + i * 16 + g * 4 + r;
        const int b = grow >> 10, n = grow & 1023;
        bits[((long)b * 12 + h) * 1024 + n] = map;
      }
    }
  }
  if (mi == 2) {
    const int b = row0 >> 10;
#pragma unroll
    for (int j = 0; j < 4; ++j) {
      float s = csum[j];
      s += __shfl_xor(s, 16);
      s += __shfl_xor(s, 32);
      if (lane < 16) atomicAdd(colsum + b * 768 + h * 64 + j * 16 + rr, s);
    }
  }
}

// ---------------- fused pruned score-verify + base GEMV ----------------
// blocks [0,768): verify (bh = bid>>3, n-tile = bid&7) with popcount prune
// blocks [768,792): base[b][oc] = colsum_b . Wo[oc,:] + bo
__global__ __launch_bounds__(256)
void k_sb(const u64* __restrict__ qbits, const u64* __restrict__ kbits,
          const float* __restrict__ colsum, const float* __restrict__ Wo,
          const float* __restrict__ bo,
          int* __restrict__ cnt, int4* __restrict__ list,
          float* __restrict__ base) {
  __shared__ __align__(16) u64 kb[1024];
  __shared__ int pkv[1024];
  __shared__ unsigned short cand[1024];  // k-row indices, desc by popcount
  __shared__ int hist[65];               // counts -> scatter cursors
  __shared__ int sufv[65];               // sufv[t] = #{m : pk[m] >= t}
  const int tid = threadIdx.x;
  const int bid = blockIdx.x;
  if (bid < 768) {
    const int bh = bid >> 3;
    const u64* src = kbits + (long)bh * 1024;
    if (tid < 65) hist[tid] = 0;
    __syncthreads();
#pragma unroll
    for (int u = 0; u < 4; ++u) {
      const int m = tid + 256 * u;
      const u64 v = src[m];
      kb[m] = v;
      const int pk = __popcll(v);
      pkv[m] = pk;
      atomicAdd(&hist[pk], 1);
    }
    __syncthreads();
    if (tid == 0) {
      int run = 0;
#pragma unroll 1
      for (int v = 64; v >= 0; --v) {
        const int c = hist[v];
        hist[v] = run;        // descending-order bucket start
        run += c;
        sufv[v] = run;        // #{pk >= v}
      }
    }
    __syncthreads();
#pragma unroll
    for (int u = 0; u < 4; ++u) {
      const int m = tid + 256 * u;
      const int pos = atomicAdd(&hist[pkv[m]], 1);
      cand[pos] = (unsigned short)m;
    }
    __syncthreads();
    // per n: only k-rows with pk >= 53 - pq can reach hd > 52 (exact bound)
    const int n = (bid & 7) * 128 + (tid >> 1);
    const u64 qb = qbits[(long)bh * 1024 + n];
    const int t = 53 - __popcll(qb);
    const int L = (t <= 0) ? 1024 : ((t > 64) ? 0 : sufv[t]);
    for (int e = (tid & 1); e < L; e += 2) {
      const int m = cand[e];
      const int hd = __popcll(qb ^ kb[m]);
      if (hd > 52) {  // score = 64 - hd < 12: exact correction needed
        const int x = atomicAdd(cnt, 1);
        if (x < 8192) list[x] = make_int4(bh, n, m, hd);
      }
    }
  } else {
    const int bb = bid - 768;  // 0..23
    const int b = bb / 3, ch = bb - b * 3;
    const int oc = ch * 256 + tid;
    const float4* c4 = (const float4*)(colsum + b * 768);
    const float4* w4 = (const float4*)(Wo + (long)oc * 768);
    float acc = bo[oc];
#pragma unroll 4
    for (int i = 0; i < 192; ++i) {
      const float4 c = c4[i], w = w4[i];
      acc += c.x * w.x + c.y * w.y + c.z * w.z + c.w * w.w;
    }
    base[b * 768 + oc] = acc;
  }
}

// ---------------- broadcast out rows (+ rare exact correction) -------------
// grid (8192), 192 thr: out[row][:] = base[b][:] (- corrections)
__global__ __launch_bounds__(192)
void k_out(const float* __restrict__ base, const int* __restrict__ cnt,
           const int4* __restrict__ list, const u64* __restrict__ vbits,
           const float* __restrict__ Wo, float* __restrict__ out) {
  const int row = blockIdx.x;
  const int b = row >> 10;
  float4 v = ((const float4*)(base + b * 768))[threadIdx.x];
  const int c = min(*cnt, 8192);
  if (c > 0) {
    const int n = row & 1023;
    for (int e = 0; e < c; ++e) {
      const int4 E = list[e];
      const int eb = E.x / 12;
      if (eb == b && E.y == n) {
        const int hh = E.x - eb * 12;
        const float s = (float)(64 - E.w);
        const float w = 1.0f / (1.0f + __expf(s));  // 1 - sigmoid(s)
        const u64 vb = vbits[(long)E.x * 1024 + E.z];
        float4 d = {0.f, 0.f, 0.f, 0.f};
        for (int dd = 0; dd < 64; ++dd)
          if ((vb >> dd) & 1ull) {
            const float* wp = Wo + (long)(threadIdx.x * 4) * 768 + hh * 64 + dd;
            d.x += wp[0]; d.y += wp[768]; d.z += wp[1536]; d.w += wp[2304];
          }
        v.x -= w * d.x; v.y -= w * d.y; v.z -= w * d.z; v.w -= w * d.w;
      }
    }
  }
  ((float4*)(out + (long)row * 768))[threadIdx.x] = v;
}

extern "C" void kernel_launch(void* const* d_in, const int* in_sizes, int n_in,
                              void* d_out, int out_size, void* d_ws, size_t ws_size,
                              hipStream_t stream) {
  const float* x  = (const float*)d_in[0];
  const float* Wq = (const float*)d_in[1];
  const float* bq = (const float*)d_in[2];
  const float* Wk = (const float*)d_in[3];
  const float* bk = (const float*)d_in[4];
  const float* Wv = (const float*)d_in[5];
  const float* bv = (const float*)d_in[6];
  const float* Wo = (const float*)d_in[7];
  const float* bo = (const float*)d_in[8];
  float* out = (float*)d_out;

  char* ws = (char*)d_ws;
  unsigned short* xb    = (unsigned short*)(ws + 0);         // 12,582,912
  unsigned short* wcat  = (unsigned short*)(ws + 12582912);  //  3,538,944
  float*          bcat  = (float*)(ws + 16121856);           //      9,216
  u64*            bits3 = (u64*)(ws + 16131072);             //  2,359,296 [3][96][1024]
  float*          colsum = (float*)(ws + 18490368);          //     24,576
  float*          base   = (float*)(ws + 18514944);          //     24,576
  int*            cnt    = (int*)(ws + 18539520);            //         16
  int4*           list   = (int4*)(ws + 18539536);           //    131,072

  const u64* qbits = bits3;
  const u64* kbits = bits3 + 98304;
  const u64* vbits = bits3 + 2 * 98304;

  k_convert<<<dim3(7881), dim3(256), 0, stream>>>(x, Wq, bq, Wk, bk, Wv, bv,
                                                  xb, wcat, bcat, cnt, colsum);
  k_qkv<<<dim3(64, 18), dim3(256), 0, stream>>>(xb, wcat, bcat, bits3, colsum);
  k_sb<<<dim3(792), dim3(256), 0, stream>>>(qbits, kbits, colsum, Wo, bo,
                                            cnt, list, base);
  k_out<<<dim3(8192), dim3(192), 0, stream>>>(base, cnt, list, vbits, Wo, out);
}

// Round 8
// 87.922 us; speedup vs baseline: 1.3411x; 1.3411x over previous
//
#include <hip/hip_runtime.h>

// SpikeDrivenSelfAttention on gfx950 — v7.
//   k_convert : f32->bf16 x, Wq|Wk|Wv; zero cnt + colsum
//   k_qkv     : 3-proj GEMM (MFMA 16x16x32, single 32KB LDS buffer) +
//               closed-form LIF threshold -> ballot-packed bit rows; V colsum
//   k_sb      : score verify, exact 2-phase prune WITHOUT sort:
//               hd>52 needs pq+pk>=53 => pq>=27 or pk>=27. Phase A: rows with
//               pq>=27 scanned cooperatively vs all m. Phase B: rows pq<27 vs
//               compacted {pk>=27} list (~40/1024). Disjoint, exact. + GEMV.
//   k_out     : broadcast base rows + sparse exact correction (normally none)

typedef __attribute__((ext_vector_type(8))) short short8;
typedef __attribute__((ext_vector_type(4))) float f32x4;
typedef unsigned long long u64;

static __device__ __forceinline__ unsigned short f2bf(float f) {
  unsigned int u = __builtin_bit_cast(unsigned int, f);
  return (unsigned short)((u + 0x7FFFu + ((u >> 16) & 1u)) >> 16);
}

static __device__ __forceinline__ u64 pack4bf(float a, float b, float c, float d) {
  return (u64)f2bf(a) | ((u64)f2bf(b) << 16) | ((u64)f2bf(c) << 32) |
         ((u64)f2bf(d) << 48);
}

static __device__ __forceinline__ void gl2lds16(const unsigned short* g,
                                                unsigned short* l) {
  __builtin_amdgcn_global_load_lds(
      (const __attribute__((address_space(1))) unsigned int*)(g),
      (__attribute__((address_space(3))) unsigned int*)(l),
      16, 0, 0);
}

// ---------------- convert: f32 -> bf16 staging + zero-init ----------------
__global__ void k_convert(const float* __restrict__ x,
                          const float* __restrict__ Wq, const float* __restrict__ bq,
                          const float* __restrict__ Wk, const float* __restrict__ bk,
                          const float* __restrict__ Wv, const float* __restrict__ bv,
                          unsigned short* __restrict__ xb,
                          unsigned short* __restrict__ wcat,
                          float* __restrict__ bcat,
                          int* __restrict__ cnt,
                          float* __restrict__ colsum) {
  const int X4 = 1572864;  // 8192*768/4
  const int W4 = 147456;   // 768*768/4
  const int NB = 576;      // 2304 bias floats / 4
  const int NZ = 1536;     // 6144 colsum floats / 4
  const int total = X4 + 3 * W4 + NB + NZ;
  int t = blockIdx.x * blockDim.x + threadIdx.x;
  if (t >= total) return;
  if (t == 0) *cnt = 0;
  if (t < X4) {
    float4 v = ((const float4*)x)[t];
    *(u64*)(xb + 4 * (long)t) = pack4bf(v.x, v.y, v.z, v.w);
  } else if (t < X4 + 3 * W4) {
    int j = t - X4;
    const float* src = Wq;
    int jj = j;
    if (jj >= 2 * W4) { src = Wv; jj -= 2 * W4; }
    else if (jj >= W4) { src = Wk; jj -= W4; }
    float4 v = ((const float4*)src)[jj];
    *(u64*)(wcat + 4 * (long)j) = pack4bf(v.x, v.y, v.z, v.w);
  } else if (t < X4 + 3 * W4 + NB) {
    int j = t - (X4 + 3 * W4);  // 0..575
    int idx = j * 4;
    const float* src = bq;
    int ii = idx;
    if (ii >= 1536) { src = bv; ii -= 1536; }
    else if (ii >= 768) { src = bk; ii -= 768; }
    float4 v = *(const float4*)(src + ii);
    *(float4*)(bcat + idx) = v;
  } else {
    int j = t - (X4 + 3 * W4 + NB);  // 0..1535
    float4 z = {0.f, 0.f, 0.f, 0.f};
    ((float4*)colsum)[j] = z;
  }
}

// ---------------- QKV GEMM + threshold LIF + bit-pack + colsum ------
// grid (64, 18): 128x128 tiles over (8192 x 2304). cols: [q|k|v].
__global__ __launch_bounds__(256, 4)
void k_qkv(const unsigned short* __restrict__ xb,
           const unsigned short* __restrict__ wcat,
           const float* __restrict__ bcat,
           u64* __restrict__ bits3,     // [3][96][1024]
           float* __restrict__ colsum)  // [8][768]
{
  __shared__ __align__(16) unsigned short lA[128 * 64];
  __shared__ __align__(16) unsigned short lB[128 * 64];
  const int tid = threadIdx.x;
  const int lane = tid & 63;
  const int wid = tid >> 6;
  const int wm = wid >> 1, wn = wid & 1;
  const int row0 = blockIdx.x * 128;
  const int col0 = blockIdx.y * 128;
  const int srow = lane >> 3;
  const int scol = (lane & 7) * 8;
  const int rr = lane & 15;
  const int g = lane >> 4;
  const int g8 = g * 8;

  // hoisted per-thread staging bases (thread-invariant across K-loop)
  const unsigned short* gA = xb + (long)(row0 + wid * 32 + srow) * 768 + scol;
  const unsigned short* gB = wcat + (long)(col0 + wid * 32 + srow) * 768 + scol;
  unsigned short* sA = &lA[(wid * 32 + srow) * 64 + scol];
  unsigned short* sB = &lB[(wid * 32 + srow) * 64 + scol];

  f32x4 acc[4][4] = {};

#pragma unroll 1
  for (int kt = 0; kt < 768; kt += 64) {
    __syncthreads();
#pragma unroll
    for (int s = 0; s < 4; ++s) {
      gl2lds16(gA + s * (8 * 768) + kt, sA + s * (8 * 64));
      gl2lds16(gB + s * (8 * 768) + kt, sB + s * (8 * 64));
    }
    __syncthreads();
#pragma unroll
    for (int kk = 0; kk < 2; ++kk) {
      const int ko = kk * 32 + g8;
      short8 af[4];
#pragma unroll
      for (int i = 0; i < 4; ++i)
        af[i] = *(const short8*)&lA[(wm * 64 + i * 16 + rr) * 64 + ko];
#pragma unroll
      for (int j = 0; j < 4; ++j) {
        const short8 bf = *(const short8*)&lB[(wn * 64 + j * 16 + rr) * 64 + ko];
#pragma unroll
        for (int i = 0; i < 4; ++i)
          acc[i][j] = __builtin_amdgcn_mfma_f32_16x16x32_bf16(af[i], bf, acc[i][j], 0, 0, 0);
      }
    }
  }

  // epilogue: closed-form LIF threshold -> ballots -> bit rows (+ colsum)
  const int mi = blockIdx.y / 6;                 // 0=q,1=k,2=v
  const int h = 2 * (blockIdx.y - mi * 6) + wn;  // head 0..11 (wave-uniform)
  u64* bits = bits3 + (long)mi * 98304;          // [96][1024]
  const float C_LIF = 0.45505041f;               // 1/(1+d+d^2+d^3), d=exp(-.5)
  float thr[4];
#pragma unroll
  for (int j = 0; j < 4; ++j) thr[j] = C_LIF - bcat[col0 + wn * 64 + j * 16 + rr];

  float csum[4] = {0.f, 0.f, 0.f, 0.f};
#pragma unroll
  for (int i = 0; i < 4; ++i) {
#pragma unroll
    for (int r = 0; r < 4; ++r) {
      u64 map = 0;
#pragma unroll
      for (int j = 0; j < 4; ++j) {
        const bool sp = acc[i][j][r] >= thr[j];
        const u64 bl = __ballot(sp);
        map |= ((bl >> (g * 16)) & 0xFFFFull) << (j * 16);
        csum[j] += sp ? 1.0f : 0.0f;
      }
      if (rr == 0) {
        const int grow = row0 + wm * 64 + i * 16 + g * 4 + r;
        const int b = grow >> 10, n = grow & 1023;
        bits[((long)b * 12 + h) * 1024 + n] = map;
      }
    }
  }
  if (mi == 2) {
    const int b = row0 >> 10;
#pragma unroll
    for (int j = 0; j < 4; ++j) {
      float s = csum[j];
      s += __shfl_xor(s, 16);
      s += __shfl_xor(s, 32);
      if (lane < 16) atomicAdd(colsum + b * 768 + h * 64 + j * 16 + rr, s);
    }
  }
}

// ---------------- fused pruned score-verify + base GEMV ----------------
// blocks [0,768): verify (bh = bid>>3, n-tile = bid&7), 2-phase exact prune
// blocks [768,792): base[b][oc] = colsum_b . Wo[oc,:] + bo
__global__ __launch_bounds__(256)
void k_sb(const u64* __restrict__ qbits, const u64* __restrict__ kbits,
          const float* __restrict__ colsum, const float* __restrict__ Wo,
          const float* __restrict__ bo,
          int* __restrict__ cnt, int4* __restrict__ list,
          float* __restrict__ base) {
  __shared__ __align__(16) u64 kb[1024];
  __shared__ u64 qs[128];
  __shared__ int pqv[128];
  __shared__ unsigned short ncList[128];   // q-rows with pq >= 27 (~5)
  __shared__ unsigned short kcList[1024];  // k-rows with pk >= 27 (~40)
  __shared__ int ncnt, kcnt;
  const int tid = threadIdx.x;
  const int bid = blockIdx.x;
  if (bid < 768) {
    const int bh = bid >> 3;
    const int ntile = (bid & 7) * 128;
    const u64* ksrc = kbits + (long)bh * 1024;
    const u64* qsrc = qbits + (long)bh * 1024 + ntile;
    if (tid == 0) { ncnt = 0; kcnt = 0; }
    __syncthreads();
#pragma unroll
    for (int u = 0; u < 4; ++u) {
      const int m = tid + 256 * u;
      const u64 v = ksrc[m];
      kb[m] = v;
      if (__popcll(v) >= 27) {
        const int p = atomicAdd(&kcnt, 1);
        kcList[p] = (unsigned short)m;
      }
    }
    if (tid < 128) {
      const u64 qv = qsrc[tid];
      qs[tid] = qv;
      const int pq = __popcll(qv);
      pqv[tid] = pq;
      if (pq >= 27) {
        const int p = atomicAdd(&ncnt, 1);
        ncList[p] = (unsigned short)tid;
      }
    }
    __syncthreads();
    // phase A: high-pq rows vs ALL m (cooperative, uniform across block)
    const int nc = ncnt;
    for (int ii = 0; ii < nc; ++ii) {
      const int n = ncList[ii];
      const u64 qb = qs[n];
#pragma unroll
      for (int u = 0; u < 4; ++u) {
        const int m = tid + 256 * u;
        const int hd = __popcll(qb ^ kb[m]);
        if (hd > 52) {  // score = 64 - hd < 12
          const int x = atomicAdd(cnt, 1);
          if (x < 8192) list[x] = make_int4(bh, ntile + n, m, hd);
        }
      }
    }
    // phase B: low-pq rows vs high-pk list (disjoint from phase A)
    const int kc = kcnt;
    const int n = tid >> 1;
    if (pqv[n] < 27) {
      const u64 qb = qs[n];
      for (int e = (tid & 1); e < kc; e += 2) {
        const int m = kcList[e];
        const int hd = __popcll(qb ^ kb[m]);
        if (hd > 52) {
          const int x = atomicAdd(cnt, 1);
          if (x < 8192) list[x] = make_int4(bh, ntile + n, m, hd);
        }
      }
    }
  } else {
    const int bb = bid - 768;  // 0..23
    const int b = bb / 3, ch = bb - b * 3;
    const int oc = ch * 256 + tid;
    const float4* c4 = (const float4*)(colsum + b * 768);
    const float4* w4 = (const float4*)(Wo + (long)oc * 768);
    float acc = bo[oc];
#pragma unroll 4
    for (int i = 0; i < 192; ++i) {
      const float4 c = c4[i], w = w4[i];
      acc += c.x * w.x + c.y * w.y + c.z * w.z + c.w * w.w;
    }
    base[b * 768 + oc] = acc;
  }
}

// ---------------- broadcast out rows (+ rare exact correction) -------------
// grid (8192), 192 thr: out[row][:] = base[b][:] (- corrections)
__global__ __launch_bounds__(192)
void k_out(const float* __restrict__ base, const int* __restrict__ cnt,
           const int4* __restrict__ list, const u64* __restrict__ vbits,
           const float* __restrict__ Wo, float* __restrict__ out) {
  const int row = blockIdx.x;
  const int b = row >> 10;
  float4 v = ((const float4*)(base + b * 768))[threadIdx.x];
  const int c = min(*cnt, 8192);
  if (c > 0) {
    const int n = row & 1023;
    for (int e = 0; e < c; ++e) {
      const int4 E = list[e];
      const int eb = E.x / 12;
      if (eb == b && E.y == n) {
        const int hh = E.x - eb * 12;
        const float s = (float)(64 - E.w);
        const float w = 1.0f / (1.0f + __expf(s));  // 1 - sigmoid(s)
        const u64 vb = vbits[(long)E.x * 1024 + E.z];
        float4 d = {0.f, 0.f, 0.f, 0.f};
        for (int dd = 0; dd < 64; ++dd)
          if ((vb >> dd) & 1ull) {
            const float* wp = Wo + (long)(threadIdx.x * 4) * 768 + hh * 64 + dd;
            d.x += wp[0]; d.y += wp[768]; d.z += wp[1536]; d.w += wp[2304];
          }
        v.x -= w * d.x; v.y -= w * d.y; v.z -= w * d.z; v.w -= w * d.w;
      }
    }
  }
  ((float4*)(out + (long)row * 768))[threadIdx.x] = v;
}

extern "C" void kernel_launch(void* const* d_in, const int* in_sizes, int n_in,
                              void* d_out, int out_size, void* d_ws, size_t ws_size,
                              hipStream_t stream) {
  const float* x  = (const float*)d_in[0];
  const float* Wq = (const float*)d_in[1];
  const float* bq = (const float*)d_in[2];
  const float* Wk = (const float*)d_in[3];
  const float* bk = (const float*)d_in[4];
  const float* Wv = (const float*)d_in[5];
  const float* bv = (const float*)d_in[6];
  const float* Wo = (const float*)d_in[7];
  const float* bo = (const float*)d_in[8];
  float* out = (float*)d_out;

  char* ws = (char*)d_ws;
  unsigned short* xb    = (unsigned short*)(ws + 0);         // 12,582,912
  unsigned short* wcat  = (unsigned short*)(ws + 12582912);  //  3,538,944
  float*          bcat  = (float*)(ws + 16121856);           //      9,216
  u64*            bits3 = (u64*)(ws + 16131072);             //  2,359,296 [3][96][1024]
  float*          colsum = (float*)(ws + 18490368);          //     24,576
  float*          base   = (float*)(ws + 18514944);          //     24,576
  int*            cnt    = (int*)(ws + 18539520);            //         16
  int4*           list   = (int4*)(ws + 18539536);           //    131,072

  const u64* qbits = bits3;
  const u64* kbits = bits3 + 98304;
  const u64* vbits = bits3 + 2 * 98304;

  k_convert<<<dim3(7881), dim3(256), 0, stream>>>(x, Wq, bq, Wk, bk, Wv, bv,
                                                  xb, wcat, bcat, cnt, colsum);
  k_qkv<<<dim3(64, 18), dim3(256), 0, stream>>>(xb, wcat, bcat, bits3, colsum);
  k_sb<<<dim3(792), dim3(256), 0, stream>>>(qbits, kbits, colsum, Wo, bo,
                                            cnt, list, base);
  k_out<<<dim3(8192), dim3(192), 0, stream>>>(base, cnt, list, vbits, Wo, out);
}